// Round 9
// baseline (396.872 us; speedup 1.0000x reference)
//
#include <hip/hip_runtime.h>

// MergeAdapter: out = x + Up_n(relu(Down_n(x))), merged expert weights.
// N=16, S=2048, H=1024, Kexp=8, D=256. fp32 in/out, bf16 MFMA internally.
//
// Round 10: UNFUSE. R4-R9 swept the fused design space (1/2 blk/CU, drain-0/
// counted vmcnt, 64/128 tiles) -- all pinned at 2.0-2.55 TB/s: the fused
// lockstep (one block through 33+ barrier segments across two dependent
// GEMMs) caps per-CU memory concurrency. Fusion only saves the R round trip
// (16.8 MB bf16 = L3-resident, nearly free). Split:
//   K1 down_kernel: R = relu(x@Wd^T+bd). grid 512, 256thr, tile 64x256,
//      BK=32, Wd-only LDS dbuf (32 KB); A-frags fp32->bf16 direct from
//      global to regs (quad-coalesced 128B lines), dbl-buffered. (256,2).
//   K2 up_kernel: out = x + R@Wu^T+bu. grid 4096, 256thr, tile 64x128,
//      4 iters BK=64, Wu-only LDS dbuf (32 KB) -> 4 blk/CU; A = R bf16x8
//      from L2/L3. (256,4).
// Simple __syncthreads dbuf (m97 pattern): wave-level overlap does the
// pipelining when occupancy exists (m114). XCD batch grouping kept.

typedef unsigned short u16;
typedef __bf16 bf16x8 __attribute__((ext_vector_type(8)));
typedef float f32x4 __attribute__((ext_vector_type(4)));

__device__ __forceinline__ u16 f2bf(float f) {
    union { float f; unsigned int i; } v; v.f = f;
    unsigned int r = v.i + 0x7fffu + ((v.i >> 16) & 1u);  // RNE
    return (u16)(r >> 16);
}

__device__ __forceinline__ bf16x8 cvt8(float4 a, float4 b) {
    union { bf16x8 v; u16 s[8]; } r;
    r.s[0]=f2bf(a.x); r.s[1]=f2bf(a.y); r.s[2]=f2bf(a.z); r.s[3]=f2bf(a.w);
    r.s[4]=f2bf(b.x); r.s[5]=f2bf(b.y); r.s[6]=f2bf(b.z); r.s[7]=f2bf(b.w);
    return r.v;
}

__device__ __forceinline__ void gload_lds16(const u16* g, u16* l) {
    __builtin_amdgcn_global_load_lds(
        (const __attribute__((address_space(1))) void*)g,
        (__attribute__((address_space(3))) void*)l,
        16, 0, 0);
}

// ---------------------------------------------------------------------------
// Kernel 0: merge weights + biases (fp32 in -> bf16 weights / fp32 biases).
// ---------------------------------------------------------------------------
__global__ __launch_bounds__(256)
void merge_kernel(const float* __restrict__ prob,
                  const float* __restrict__ w_down, const float* __restrict__ b_down,
                  const float* __restrict__ w_up,   const float* __restrict__ b_up,
                  u16* __restrict__ Wd, u16* __restrict__ Wu,
                  float* __restrict__ bd, float* __restrict__ bu)
{
    __shared__ float sp[128];          // prob (16 x 8)
    const int tid = threadIdx.x;
    if (tid < 128) sp[tid] = prob[tid];
    __syncthreads();

    const int bid = blockIdx.x;
    const int E = 256 * 1024;

    if (bid < 256) {
        int v = bid * 256 + tid;       // 0..65535 vector slots (8 elems each)
        const bool down = (v < 32768);
        const int vv = down ? v : (v - 32768);
        const float* W = down ? w_down : w_up;
        u16* O = down ? Wd : Wu;
        const size_t e = (size_t)vv * 8;

        float wf[8][8];
        #pragma unroll
        for (int k = 0; k < 8; ++k) {
            const float4 f0 = *(const float4*)(W + (size_t)k * E + e);
            const float4 f1 = *(const float4*)(W + (size_t)k * E + e + 4);
            wf[k][0] = f0.x; wf[k][1] = f0.y; wf[k][2] = f0.z; wf[k][3] = f0.w;
            wf[k][4] = f1.x; wf[k][5] = f1.y; wf[k][6] = f1.z; wf[k][7] = f1.w;
        }
        for (int n = 0; n < 16; ++n) {
            float a[8] = {0.f,0.f,0.f,0.f,0.f,0.f,0.f,0.f};
            #pragma unroll
            for (int k = 0; k < 8; ++k) {
                const float p = sp[n * 8 + k];
                #pragma unroll
                for (int j = 0; j < 8; ++j) a[j] = fmaf(p, wf[k][j], a[j]);
            }
            union { uint4 u; u16 s[8]; } ov;
            #pragma unroll
            for (int j = 0; j < 8; ++j) ov.s[j] = f2bf(a[j]);
            *(uint4*)(O + (size_t)n * E + e) = ov.u;
        }
    } else {
        int idx = (bid - 256) * 256 + tid;   // 0..20479
        if (idx < 16 * 256) {
            const int n = idx >> 8, d = idx & 255;
            float s = 0.f;
            #pragma unroll
            for (int k = 0; k < 8; ++k)
                s = fmaf(sp[n * 8 + k], b_down[k * 256 + d], s);
            bd[idx] = s;
        } else {
            const int i2 = idx - 4096;
            const int n = i2 >> 10, h = i2 & 1023;
            float s = 0.f;
            #pragma unroll
            for (int k = 0; k < 8; ++k)
                s = fmaf(sp[n * 8 + k], b_up[k * 1024 + h], s);
            bu[i2] = s;
        }
    }
}

// ---------------------------------------------------------------------------
// K1: R = relu(x @ Wd^T + bd). Grid 512 (2 blk/CU), 256 thr (4 waves).
// Tile 64x256, BK=32, 32 iters. Wd in LDS dbuf; A direct global->reg.
// ---------------------------------------------------------------------------
__global__ __launch_bounds__(256, 2)
void down_kernel(const float* __restrict__ x, const u16* __restrict__ Wd,
                 const float* __restrict__ bd, u16* __restrict__ R)
{
    __shared__ __align__(16) u16 wdl[2][8192];   // 2 x 16 KB (256 rows x 32)

    const int tid  = threadIdx.x;
    const int lane = tid & 63;
    const int wave = tid >> 6;               // 0..3 (N-split)
    const int quad = lane >> 4, rl = lane & 15;

    const int id = blockIdx.x;               // 0..511
    const int batch = (id & 7) * 2 + ((id >> 3) & 1);
    const int mblk  = id >> 4;               // 0..31

    const float* xb  = x  + (size_t)batch * 2048 * 1024 + (size_t)mblk * 64 * 1024;
    const u16*   Wdb = Wd + (size_t)batch * 256 * 1024;
    const float* bdb = bd + batch * 256;
    u16*         Rb  = R  + (size_t)batch * 2048 * 256 + (size_t)mblk * 64 * 256;

    float bdv[4];
    #pragma unroll
    for (int ni = 0; ni < 4; ++ni) bdv[ni] = bdb[wave * 64 + ni * 16 + rl];

    // Wd staging: 4 DMA/thread; rows r*64 + wave*16 + (lane>>2), slot lane&3.
    // Swizzle: phys slot (lane&3) holds logical slot (lane&3)^(row&3)
    // (XOR on the global source col; involutive).
    const int srow = lane >> 2, sslot = lane & 3;
    auto stage = [&](int it, int b) {
        const int kt = it * 32;
        #pragma unroll
        for (int r = 0; r < 4; ++r) {
            const int row = r * 64 + wave * 16 + srow;
            gload_lds16(Wdb + (size_t)row * 1024 + kt + ((sslot ^ (row & 3)) * 8),
                        wdl[b] + r * 2048 + wave * 512);
        }
    };

    // A fragments: mi-th row group, quad's 8 k-elems, fp32->bf16 in regs.
    auto ldA = [&](int it, bf16x8* av) {
        #pragma unroll
        for (int mi = 0; mi < 4; ++mi) {
            const float* p = xb + (size_t)(mi * 16 + rl) * 1024 + it * 32 + quad * 8;
            av[mi] = cvt8(*(const float4*)p, *(const float4*)(p + 4));
        }
    };

    f32x4 acc[4][4] = {};
    auto comp = [&](const u16* buf, const bf16x8* av) {
        #pragma unroll
        for (int ni = 0; ni < 4; ++ni) {
            const int c = wave * 64 + ni * 16 + rl;
            const bf16x8 bv = *(const bf16x8*)(buf + c * 32 + (quad ^ (rl & 3)) * 8);
            #pragma unroll
            for (int mi = 0; mi < 4; ++mi)
                acc[mi][ni] = __builtin_amdgcn_mfma_f32_16x16x32_bf16(
                    av[mi], bv, acc[mi][ni], 0, 0, 0);
        }
    };

    bf16x8 avA[4], avB[4];
    ldA(0, avA);
    stage(0, 0);
    __syncthreads();

    #pragma unroll 2
    for (int p = 0; p < 16; ++p) {
        const int e = 2 * p;                  // even iter: uses avA, wdl[0]
        if (e < 31) { stage(e + 1, 1); ldA(e + 1, avB); }
        comp(wdl[0], avA);
        __syncthreads();
        const int o = e + 1;                  // odd iter: uses avB, wdl[1]
        if (o < 31) { stage(o + 1, 0); ldA(o + 1, avA); }
        comp(wdl[1], avB);
        __syncthreads();
    }

    // epilogue: bias + relu -> R bf16
    #pragma unroll
    for (int ni = 0; ni < 4; ++ni) {
        const int col = wave * 64 + ni * 16 + rl;
        #pragma unroll
        for (int mi = 0; mi < 4; ++mi)
            #pragma unroll
            for (int i = 0; i < 4; ++i) {
                const int row = mi * 16 + quad * 4 + i;
                Rb[(size_t)row * 256 + col] =
                    f2bf(fmaxf(acc[mi][ni][i] + bdv[ni], 0.0f));
            }
    }
}

// ---------------------------------------------------------------------------
// K2: out = x + R @ Wu^T + bu. Grid 4096 (4 blk/CU), 256 thr (4 waves).
// Tile 64x128, K=256 in 4 BK=64 steps. Wu in LDS dbuf; A = R from L2/L3.
// ---------------------------------------------------------------------------
__global__ __launch_bounds__(256, 4)
void up_kernel(const float* __restrict__ x, const u16* __restrict__ Wu,
               const float* __restrict__ bu, const u16* __restrict__ R,
               float* __restrict__ out)
{
    __shared__ __align__(16) u16 wul[2][8192];   // 2 x 16 KB (128 rows x 64)

    const int tid  = threadIdx.x;
    const int lane = tid & 63;
    const int wave = tid >> 6;               // 0..3 (N-split, 32 cols each)
    const int quad = lane >> 4, rl = lane & 15;

    const int id = blockIdx.x;               // 0..4095
    const int batch = (id & 7) * 2 + ((id >> 3) & 1);
    const int rest  = id >> 4;               // 0..255
    const int mblk  = rest & 31;             // 0..31
    const int nblk  = rest >> 5;             // 0..7

    const u16* Rb = R + (size_t)batch * 2048 * 256 + (size_t)mblk * 64 * 256;
    const size_t base = (size_t)batch * 2048 * 1024 + (size_t)mblk * 64 * 1024
                      + (size_t)nblk * 128;
    const float* xb  = x + base;
    float*       ob  = out + base;
    const u16*   Wub = Wu + (size_t)batch * 1024 * 256 + (size_t)nblk * 128 * 256;
    const float* bub2 = bu + batch * 1024 + nblk * 128;

    float buv[2];
    #pragma unroll
    for (int ni = 0; ni < 2; ++ni) buv[ni] = bub2[wave * 32 + ni * 16 + rl];

    // Wu staging: 4 DMA/thread; rows r*32 + wave*8 + (lane>>3), slot lane&7.
    const int srow = lane >> 3, sslot = lane & 7;
    auto stage = [&](int it, int b) {
        const int kt = it * 64;
        #pragma unroll
        for (int r = 0; r < 4; ++r) {
            const int row = r * 32 + wave * 8 + srow;
            gload_lds16(Wub + (size_t)row * 256 + kt + ((sslot ^ (row & 7)) * 8),
                        wul[b] + r * 2048 + wave * 512);
        }
    };

    f32x4 acc[4][2] = {};

    stage(0, 0);
    __syncthreads();

    #pragma unroll
    for (int it = 0; it < 4; ++it) {
        const int cur = it & 1;
        if (it < 3) stage(it + 1, cur ^ 1);
        #pragma unroll
        for (int kk = 0; kk < 2; ++kk) {
            bf16x8 av[4];
            #pragma unroll
            for (int mi = 0; mi < 4; ++mi)
                av[mi] = *(const bf16x8*)(Rb + (size_t)(mi * 16 + rl) * 256
                                          + it * 64 + kk * 32 + quad * 8);
            #pragma unroll
            for (int ni = 0; ni < 2; ++ni) {
                const int c = wave * 32 + ni * 16 + rl;
                const bf16x8 bv = *(const bf16x8*)(wul[cur] + c * 64
                                    + (((kk * 4 + quad) ^ (rl & 7)) * 8));
                #pragma unroll
                for (int mi = 0; mi < 4; ++mi)
                    acc[mi][ni] = __builtin_amdgcn_mfma_f32_16x16x32_bf16(
                        av[mi], bv, acc[mi][ni], 0, 0, 0);
            }
        }
        __syncthreads();
    }

    // epilogue: bias + fp32 residual -> fp32 out
    #pragma unroll
    for (int ni = 0; ni < 2; ++ni) {
        const int coll = wave * 32 + ni * 16 + rl;
        #pragma unroll
        for (int mi = 0; mi < 4; ++mi)
            #pragma unroll
            for (int i = 0; i < 4; ++i) {
                const int rowl = mi * 16 + quad * 4 + i;
                const size_t off = (size_t)rowl * 1024 + coll;
                ob[off] = acc[mi][ni][i] + buv[ni] + xb[off];
            }
    }
}

// ---------------------------------------------------------------------------
extern "C" void kernel_launch(void* const* d_in, const int* in_sizes, int n_in,
                              void* d_out, int out_size, void* d_ws, size_t ws_size,
                              hipStream_t stream) {
    const float* hidden = (const float*)d_in[0];   // (16, 2048, 1024) fp32
    const float* prob   = (const float*)d_in[1];   // (16, 8) fp32
    const float* w_down = (const float*)d_in[2];   // (8, 256, 1024) fp32
    const float* b_down = (const float*)d_in[3];   // (8, 256) fp32
    const float* w_up   = (const float*)d_in[4];   // (8, 1024, 256) fp32
    const float* b_up   = (const float*)d_in[5];   // (8, 1024) fp32
    float* out = (float*)d_out;                    // (16, 2048, 1024) fp32

    // workspace: merged weights (bf16) + biases (fp32) + R (bf16), ~33.7 MB
    u16* Wd = (u16*)d_ws;                               // 16*256*1024 bf16
    u16* Wu = Wd + (size_t)16 * 256 * 1024;             // 16*1024*256 bf16
    float* bd = (float*)(Wu + (size_t)16 * 1024 * 256); // 16*256 f32
    float* bu = bd + 16 * 256;                          // 16*1024 f32
    u16* R  = (u16*)(bu + 16 * 1024);                   // 16*2048*256 bf16

    merge_kernel<<<336, 256, 0, stream>>>(prob, w_down, b_down, w_up, b_up,
                                          Wd, Wu, bd, bu);

    down_kernel<<<512, 256, 0, stream>>>(hidden, Wd, bd, R);

    up_kernel<<<4096, 256, 0, stream>>>(hidden, Wu, bu, R, out);
}